// Round 11
// baseline (506.955 us; speedup 1.0000x reference)
//
#include <hip/hip_runtime.h>
#include <hip/hip_bf16.h>
#include <stdint.h>

#define NN 50000
#define NE 800000
#define NB 196            // dst buckets: dst>>8 (256 nodes each)
#define EPB 2048
#define NBLK ((NE + EPB - 1) / EPB)   // 391
#define BCAP 8192         // per-bucket staging capacity (max bucket ~4350)
#define NGRP 782          // ceil(NN/64) node-groups per slice

typedef __attribute__((ext_vector_type(8))) __bf16 bf16x8;
typedef __attribute__((ext_vector_type(4))) float f32x4;
typedef __attribute__((ext_vector_type(4))) int i32x4;

__device__ __forceinline__ float bflo(uint32_t u) { return __uint_as_float(u << 16); }
__device__ __forceinline__ float bfhi(uint32_t u) { return __uint_as_float(u & 0xffff0000u); }
__device__ __forceinline__ uint16_t f2bf(float f) {
    uint32_t u = __float_as_uint(f);
    u += 0x7fffu + ((u >> 16) & 1u);   // RNE
    return (uint16_t)(u >> 16);
}
__device__ __forceinline__ float bf2f(uint16_t h) { return __uint_as_float(((uint32_t)h) << 16); }

// bijective XCD-chunked block swizzle (m204 variant)
__device__ __forceinline__ int xcd_swz(int bid, int nwg) {
    int q = nwg >> 3, r = nwg & 7;
    int xcd = bid & 7, idx = bid >> 3;
    int base = (xcd < r) ? xcd * (q + 1) : r * (q + 1) + (xcd - r) * q;
    return base + idx;
}

// per-block edge-layout detection (int64 vs int32)
__device__ __forceinline__ int detect_i64(const int* ei, int* sh_cnt) {
    int t = threadIdx.x;
    if (t == 0) *sh_cnt = 0;
    __syncthreads();
    if (t < 64) atomicAdd(sh_cnt, (ei[2 * t + 1] != 0) ? 1 : 0);
    __syncthreads();
    return (*sh_cnt < 4) ? 1 : 0;
}

// per-block x-dtype detection (fp32 vs bf16)
__device__ __forceinline__ int detect_fp32(const uint32_t* xu, int* sh_cnt) {
    int t = threadIdx.x;
    if (t == 0) *sh_cnt = 0;
    __syncthreads();
    uint32_t u = xu[t & 255];
    uint32_t lo = u & 0xffffu;
    uint32_t e = (lo >> 7) & 0xffu;
    int ok = (lo == 0u) || (e >= 96u && e <= 150u);
    if (t < 256) atomicAdd(sh_cnt, ok);
    __syncthreads();
    return (*sh_cnt < 192) ? 1 : 0;
}

// ---------------- prep kernel 1: count + reserve + scatter (single kernel) ----------------
__global__ __launch_bounds__(256) void scatter1(const int* __restrict__ ei,
                                                int* __restrict__ bucket_cur,
                                                uint32_t* __restrict__ staging) {
    __shared__ int hist[NB];
    __shared__ int curs[NB];
    __shared__ int shc;
    int fl = detect_i64(ei, &shc);
    int t = threadIdx.x;
    for (int i = t; i < NB; i += 256) hist[i] = 0;
    __syncthreads();
    int base = blockIdx.x * EPB;
    for (int i = 0; i < EPB; i += 256) {   // pass 1: count
        int e = base + i + t;
        if (e < NE) {
            int d = fl ? ei[2 * NE + 2 * e] : ei[NE + e];
            atomicAdd(&hist[d >> 8], 1);
        }
    }
    __syncthreads();
    for (int i = t; i < NB; i += 256)      // reserve runs
        curs[i] = (hist[i] > 0) ? atomicAdd(&bucket_cur[i], hist[i]) : 0;
    __syncthreads();
    for (int i = 0; i < EPB; i += 256) {   // pass 2: scatter (ei re-read from L2)
        int e = base + i + t;
        if (e < NE) {
            int s, d;
            if (fl) { s = ei[2 * e]; d = ei[2 * NE + 2 * e]; }
            else    { s = ei[e];     d = ei[NE + e]; }
            int b = d >> 8;
            int p = atomicAdd(&curs[b], 1);
            staging[b * BCAP + p] = ((uint32_t)(d & 0xff) << 16) | (uint32_t)s;
        }
    }
}

// ---------------- prep kernel 2 (role-split): CSR build + x-norm + weight swizzle ----------------
#define NORMX_BLKS 6250   // NN*32/256
__global__ __launch_bounds__(256) void csr_norm(const uint32_t* __restrict__ staging,
                                                const int* __restrict__ bucket_cur,
                                                const void* __restrict__ x,
                                                const void* __restrict__ w1l, const void* __restrict__ b1,
                                                const void* __restrict__ w1r, const void* __restrict__ w2l,
                                                const void* __restrict__ b2, const void* __restrict__ w2r,
                                                int* __restrict__ row_start, int* __restrict__ deg,
                                                float* __restrict__ inv_deg, int* __restrict__ csr,
                                                uint32_t* __restrict__ xb,
                                                uint16_t* __restrict__ w1l_sw, uint16_t* __restrict__ w1r_sw,
                                                uint16_t* __restrict__ w2l_sw, uint16_t* __restrict__ w2r_sw,
                                                uint16_t* __restrict__ bias_buf) {
    int blk = blockIdx.x;
    int t = threadIdx.x;
    if (blk < NB) {
        __shared__ int degs[256];
        __shared__ int sm[256];
        __shared__ int curs[256];
        int beg = blk * BCAP, cnt = bucket_cur[blk];
        degs[t] = 0;
        __syncthreads();
        for (int i = t; i < cnt; i += 256) atomicAdd(&degs[(staging[beg + i] >> 16) & 0xff], 1);
        __syncthreads();
        int d = degs[t];
        sm[t] = d;
        __syncthreads();
        for (int o = 1; o < 256; o <<= 1) {
            int x2 = (t >= o) ? sm[t - o] : 0;
            __syncthreads();
            sm[t] += x2;
            __syncthreads();
        }
        int excl = sm[t] - d;
        curs[t] = excl;
        int node = blk * 256 + t;
        if (node < NN) {
            row_start[node] = beg + excl;
            deg[node] = d;
            inv_deg[node] = 1.0f / (float)(d > 0 ? d : 1);
        }
        __syncthreads();
        for (int i = t; i < cnt; i += 256) {
            uint32_t u = staging[beg + i];
            int dl = (u >> 16) & 0xff;
            int p = atomicAdd(&curs[dl], 1);
            csr[beg + p] = (int)(u & 0xffffu);
        }
        return;
    }
    __shared__ int shc;
    int fp32 = detect_fp32((const uint32_t*)x, &shc);
    int nb = blk - NB;
    if (nb < NORMX_BLKS) {
        int i = nb * 256 + t;  // < NN*32
        if (fp32) {
            f32x4 v = ((const f32x4*)x)[i];
            uint2 o;
            o.x = (uint32_t)f2bf(v[0]) | ((uint32_t)f2bf(v[1]) << 16);
            o.y = (uint32_t)f2bf(v[2]) | ((uint32_t)f2bf(v[3]) << 16);
            ((uint2*)xb)[i] = o;
        } else {
            ((uint2*)xb)[i] = ((const uint2*)x)[i];
        }
        return;
    }
    int tid = (nb - NORMX_BLKS) * 256 + t;
    if (tid < 16384) {
        int frag = tid >> 6, lane = tid & 63;
        const void* srcw; uint16_t* dst; int N; int fl;
        if (frag < 64)       { srcw = w1l; dst = w1l_sw; N = 256; fl = frag; }
        else if (frag < 128) { srcw = w1r; dst = w1r_sw; N = 256; fl = frag - 64; }
        else if (frag < 192) { srcw = w2l; dst = w2l_sw; N = 128; fl = frag - 128; }
        else                 { srcw = w2r; dst = w2r_sw; N = 128; fl = frag - 192; }
        int NTm = N >> 4;
        int kt = fl / NTm, nt = fl - kt * NTm;
        int k0 = kt * 32 + (lane >> 4) * 8, n = nt * 16 + (lane & 15);
        uint16_t* d = dst + (size_t)fl * 512 + lane * 8;
#pragma unroll
        for (int j = 0; j < 8; j++) {
            int si = (k0 + j) * N + n;
            d[j] = fp32 ? f2bf(((const float*)srcw)[si]) : ((const uint16_t*)srcw)[si];
        }
    } else if (tid < 16384 + 384) {
        int j = tid - 16384;
        const void* s = (j < 256) ? b1 : b2;
        int jj = (j < 256) ? j : j - 256;
        bias_buf[j] = fp32 ? f2bf(((const float*)s)[jj]) : ((const uint16_t*)s)[jj];
    }
}

// ---------------- mean aggregation v2 (CONTROL, unchanged): 2 nodes/wave, dwordx2 gathers ----
__global__ __launch_bounds__(256) void agg_mean_v2(const uint32_t* __restrict__ xu,
                                                   const int* __restrict__ row_start,
                                                   const int* __restrict__ deg,
                                                   const int* __restrict__ csr,
                                                   const float* __restrict__ inv_deg,
                                                   uint32_t* __restrict__ outu) {
    int wave = threadIdx.x >> 6, lane = threadIdx.x & 63;
    int half = lane >> 5, l = lane & 31;
    int node = blockIdx.x * 8 + wave * 2 + half;
    int beg = row_start[node], end = beg + deg[node];
    float lx[8], hx[8], ly[8], hy[8];
#pragma unroll
    for (int k = 0; k < 8; k++) { lx[k] = 0.f; hx[k] = 0.f; ly[k] = 0.f; hy[k] = 0.f; }
    int j = beg;
    for (; j + 8 <= end; j += 8) {
        int idx[8];
#pragma unroll
        for (int k = 0; k < 8; k++) idx[k] = csr[j + k];
#pragma unroll
        for (int k = 0; k < 8; k++) {
            uint2 v = *(const uint2*)(xu + (size_t)idx[k] * 64 + l * 2);
            lx[k] += bflo(v.x); hx[k] += bfhi(v.x);
            ly[k] += bflo(v.y); hy[k] += bfhi(v.y);
        }
    }
    for (; j < end; j++) {
        uint2 v = *(const uint2*)(xu + (size_t)csr[j] * 64 + l * 2);
        lx[0] += bflo(v.x); hx[0] += bfhi(v.x);
        ly[0] += bflo(v.y); hy[0] += bfhi(v.y);
    }
    float sc = inv_deg[node];
    float r0 = (((lx[0] + lx[1]) + (lx[2] + lx[3])) + ((lx[4] + lx[5]) + (lx[6] + lx[7]))) * sc;
    float r1 = (((hx[0] + hx[1]) + (hx[2] + hx[3])) + ((hx[4] + hx[5]) + (hx[6] + hx[7]))) * sc;
    float r2 = (((ly[0] + ly[1]) + (ly[2] + ly[3])) + ((ly[4] + ly[5]) + (ly[6] + ly[7]))) * sc;
    float r3 = (((hy[0] + hy[1]) + (hy[2] + hy[3])) + ((hy[4] + hy[5]) + (hy[6] + hy[7]))) * sc;
    uint2 o;
    o.x = (uint32_t)f2bf(r0) | ((uint32_t)f2bf(r1) << 16);
    o.y = (uint32_t)f2bf(r2) | ((uint32_t)f2bf(r3) << 16);
    *(uint2*)(outu + (size_t)node * 64 + l * 2) = o;
}

// ---------------- agg_final_q (EXPERIMENT): XCD-affine dim-sliced gather ----------------
// Each block reads its physical XCD id (HW_REG_XCC_ID) and pulls node-groups for
// slice s = its own XCD's 16-dim column-slice from a per-slice atomic queue, then
// steals from other slices for completeness. If bid->XCD is round-robin OR chunked
// OR anything else, each XCD still gathers (almost) only its 1.6 MB slice -> L2-resident.
// Half-wave per node, 4 lanes per edge (uint2 = 4 dims), 8 edges in flight.
__global__ __launch_bounds__(256) void agg_final_q(const uint32_t* __restrict__ tu,
                                                   const int* __restrict__ row_start,
                                                   const int* __restrict__ deg,
                                                   const int* __restrict__ csr,
                                                   const float* __restrict__ inv_deg,
                                                   const float* __restrict__ u,
                                                   int* __restrict__ qctr,   // 8 zeroed counters
                                                   float* __restrict__ out) {
    __shared__ int sh_idx;
    int t = threadIdx.x;
    int hw = t >> 5, l = t & 31;
    int esub = l >> 2, dpair = l & 3;
    uint32_t myxcd;
    asm volatile("s_getreg_b32 %0, hwreg(HW_REG_XCC_ID)" : "=s"(myxcd));
    myxcd &= 7u;
    for (int ss = 0; ss < 8; ss++) {
        int s = (int)((myxcd + ss) & 7u);
        int colu = s * 8 + dpair * 2;
        while (true) {
            __syncthreads();
            if (t == 0) sh_idx = atomicAdd(&qctr[s], 1);
            __syncthreads();
            int g = sh_idx;
            if (g >= NGRP) break;
            for (int it = 0; it < 8; it++) {
                int node = g * 64 + hw * 8 + it;
                if (node >= NN) break;
                int beg = row_start[node], d = deg[node];
                float f0 = 0.f, f1 = 0.f, f2 = 0.f, f3 = 0.f;
                int j = 0;
                for (; j + 16 <= d; j += 16) {
                    int i0 = csr[beg + j + esub];
                    int i1 = csr[beg + j + 8 + esub];
                    uint2 v0 = *(const uint2*)(tu + (size_t)i0 * 64 + colu);
                    uint2 v1 = *(const uint2*)(tu + (size_t)i1 * 64 + colu);
                    f0 += bflo(v0.x) + bflo(v1.x);
                    f1 += bfhi(v0.x) + bfhi(v1.x);
                    f2 += bflo(v0.y) + bflo(v1.y);
                    f3 += bfhi(v0.y) + bfhi(v1.y);
                }
                for (; j < d; j += 8) {
                    if (j + esub < d) {
                        int i0 = csr[beg + j + esub];
                        uint2 v0 = *(const uint2*)(tu + (size_t)i0 * 64 + colu);
                        f0 += bflo(v0.x); f1 += bfhi(v0.x);
                        f2 += bflo(v0.y); f3 += bfhi(v0.y);
                    }
                }
#pragma unroll
                for (int mask = 4; mask <= 16; mask <<= 1) {
                    f0 += __shfl_xor(f0, mask);
                    f1 += __shfl_xor(f1, mask);
                    f2 += __shfl_xor(f2, mask);
                    f3 += __shfl_xor(f3, mask);
                }
                if (esub == 0) {
                    float sc = inv_deg[node];
                    f32x4 uv = *(const f32x4*)(u + (size_t)node * 128 + s * 16 + dpair * 4);
                    f32x4 r;
                    r[0] = f0 * sc + uv[0];
                    r[1] = f1 * sc + uv[1];
                    r[2] = f2 * sc + uv[2];
                    r[3] = f3 * sc + uv[3];
                    __builtin_nontemporal_store(r, (f32x4*)(out + (size_t)node * 128 + s * 16 + dpair * 4));
                }
            }
        }
    }
}

// ---------------- fused MLP (round-8 version, 64 rows x 8 waves): h(LDS) -> t, u ----------------
#define HW 264
__global__ __launch_bounds__(512) void fused_mlp(const uint16_t* __restrict__ AGG,
                                                 const uint16_t* __restrict__ XB,
                                                 const uint16_t* __restrict__ W1Lsw,
                                                 const uint16_t* __restrict__ W1Rsw,
                                                 const uint16_t* __restrict__ W2Lsw,
                                                 const uint16_t* __restrict__ W2Rsw,
                                                 const uint16_t* __restrict__ bias,   // [0..255]=b1, [256..383]=b2
                                                 uint16_t* __restrict__ T,
                                                 float* __restrict__ U) {
    __shared__ __align__(16) uint16_t hbuf[64 * HW];   // 33792 B, reused 3 ways
    int wg = xcd_swz(blockIdx.x, 782);
    int node0 = wg * 64;
    int tid = threadIdx.x;
    int wave = tid >> 6, lane = tid & 63;
    int wr = wave >> 2, wc = wave & 3;   // 2 row-halves x 4 col-quarters
    int m = lane & 15, q = lane >> 4;

    int ar[2];
#pragma unroll
    for (int rf = 0; rf < 2; rf++) {
        int r = node0 + wr * 32 + rf * 16 + m;
        ar[rf] = (r < NN) ? r : (NN - 1);
    }

    // ---- phase 1: h[64][256] = relu(agg@W1l + x@W1r + b1); wave tile 32x64 ----
    {
        f32x4 acc[2][4];
#pragma unroll
        for (int rf = 0; rf < 2; rf++)
#pragma unroll
            for (int nt = 0; nt < 4; nt++)
#pragma unroll
                for (int i = 0; i < 4; i++) acc[rf][nt][i] = 0.f;

#pragma unroll
        for (int kt = 0; kt < 4; kt++) {
            bf16x8 a10 = *(const bf16x8*)(AGG + (size_t)ar[0] * 128 + kt * 32 + q * 8);
            bf16x8 a11 = *(const bf16x8*)(AGG + (size_t)ar[1] * 128 + kt * 32 + q * 8);
            bf16x8 a20 = *(const bf16x8*)(XB + (size_t)ar[0] * 128 + kt * 32 + q * 8);
            bf16x8 a21 = *(const bf16x8*)(XB + (size_t)ar[1] * 128 + kt * 32 + q * 8);
#pragma unroll
            for (int nt = 0; nt < 4; nt++) {
                int gnt = wc * 4 + nt;   // NTF=16
                bf16x8 B1 = *(const bf16x8*)(W1Lsw + ((size_t)(kt * 16 + gnt)) * 512 + lane * 8);
                bf16x8 B2 = *(const bf16x8*)(W1Rsw + ((size_t)(kt * 16 + gnt)) * 512 + lane * 8);
                acc[0][nt] = __builtin_amdgcn_mfma_f32_16x16x32_bf16(a10, B1, acc[0][nt], 0, 0, 0);
                acc[1][nt] = __builtin_amdgcn_mfma_f32_16x16x32_bf16(a11, B1, acc[1][nt], 0, 0, 0);
                acc[0][nt] = __builtin_amdgcn_mfma_f32_16x16x32_bf16(a20, B2, acc[0][nt], 0, 0, 0);
                acc[1][nt] = __builtin_amdgcn_mfma_f32_16x16x32_bf16(a21, B2, acc[1][nt], 0, 0, 0);
            }
        }
        // epilogue 1: bias + relu -> hbuf
#pragma unroll
        for (int rf = 0; rf < 2; rf++)
#pragma unroll
            for (int nt = 0; nt < 4; nt++) {
                int cl = wc * 64 + nt * 16 + m;
                float bv = bf2f(bias[cl]);
#pragma unroll
                for (int i = 0; i < 4; i++) {
                    float v = fmaxf(acc[rf][nt][i] + bv, 0.f);
                    hbuf[(wr * 32 + rf * 16 + q * 4 + i) * HW + cl] = f2bf(v);
                }
            }
    }
    __syncthreads();

    // ---- phase 2: t = h@W2l, u = h@W2r + b2; wave tile 32x32 each, K=256 from LDS ----
    f32x4 acc1[2][2], acc2[2][2];
#pragma unroll
    for (int rf = 0; rf < 2; rf++)
#pragma unroll
        for (int nt = 0; nt < 2; nt++)
#pragma unroll
            for (int i = 0; i < 4; i++) { acc1[rf][nt][i] = 0.f; acc2[rf][nt][i] = 0.f; }

#pragma unroll
    for (int kt = 0; kt < 8; kt++) {
        bf16x8 a0 = *(const bf16x8*)&hbuf[(wr * 32 + m) * HW + kt * 32 + q * 8];
        bf16x8 a1 = *(const bf16x8*)&hbuf[(wr * 32 + 16 + m) * HW + kt * 32 + q * 8];
#pragma unroll
        for (int nt = 0; nt < 2; nt++) {
            int gnt = wc * 2 + nt;   // NTF=8
            bf16x8 BL = *(const bf16x8*)(W2Lsw + ((size_t)(kt * 8 + gnt)) * 512 + lane * 8);
            bf16x8 BR = *(const bf16x8*)(W2Rsw + ((size_t)(kt * 8 + gnt)) * 512 + lane * 8);
            acc1[0][nt] = __builtin_amdgcn_mfma_f32_16x16x32_bf16(a0, BL, acc1[0][nt], 0, 0, 0);
            acc1[1][nt] = __builtin_amdgcn_mfma_f32_16x16x32_bf16(a1, BL, acc1[1][nt], 0, 0, 0);
            acc2[0][nt] = __builtin_amdgcn_mfma_f32_16x16x32_bf16(a0, BR, acc2[0][nt], 0, 0, 0);
            acc2[1][nt] = __builtin_amdgcn_mfma_f32_16x16x32_bf16(a1, BR, acc2[1][nt], 0, 0, 0);
        }
    }
    __syncthreads();   // all waves done reading hbuf

    // ---- epilogue t: stage bf16 [64][136] in hbuf, coalesced store ----
    {
        uint16_t* st = hbuf;   // [64][136] = 17408 B
#pragma unroll
        for (int rf = 0; rf < 2; rf++)
#pragma unroll
            for (int nt = 0; nt < 2; nt++) {
                int cl = wc * 32 + nt * 16 + m;
#pragma unroll
                for (int i = 0; i < 4; i++)
                    st[(wr * 32 + rf * 16 + q * 4 + i) * 136 + cl] = f2bf(acc1[rf][nt][i]);
            }
        __syncthreads();
#pragma unroll
        for (int rr = 0; rr < 2; rr++) {
            int row = rr * 32 + (tid >> 4);
            int grow = node0 + row;
            if (grow < NN)
                *(i32x4*)(T + (size_t)grow * 128 + (tid & 15) * 8) =
                    *(const i32x4*)&st[row * 136 + (tid & 15) * 8];
        }
        __syncthreads();
    }

    // ---- epilogue u: stage fp32 [64][132] in hbuf, coalesced store ----
    {
        float* su = (float*)hbuf;   // [64][132] = 33792 B (exactly hbuf)
#pragma unroll
        for (int rf = 0; rf < 2; rf++)
#pragma unroll
            for (int nt = 0; nt < 2; nt++) {
                int cl = wc * 32 + nt * 16 + m;
                float bv = bf2f(bias[256 + cl]);
#pragma unroll
                for (int i = 0; i < 4; i++)
                    su[(wr * 32 + rf * 16 + q * 4 + i) * 132 + cl] = acc2[rf][nt][i] + bv;
            }
        __syncthreads();
#pragma unroll
        for (int rr = 0; rr < 4; rr++) {
            int row = rr * 16 + (tid >> 5);
            int grow = node0 + row;
            if (grow < NN)
                *(f32x4*)(U + (size_t)grow * 128 + (tid & 31) * 4) =
                    *(const f32x4*)&su[row * 132 + (tid & 31) * 4];
        }
    }
}

extern "C" void kernel_launch(void* const* d_in, const int* in_sizes, int n_in,
                              void* d_out, int out_size, void* d_ws, size_t ws_size,
                              hipStream_t stream) {
    const void* x_raw  = d_in[0];
    const int*  ei     = (const int*)d_in[1];
    const void* W1l    = d_in[2];
    const void* b1     = d_in[3];
    const void* W1r    = d_in[4];
    const void* W2l    = d_in[5];
    const void* b2     = d_in[6];
    const void* W2r    = d_in[7];

    uint8_t* ws = (uint8_t*)d_ws;
    size_t off = 0;
    auto alloc = [&](size_t b) -> void* {
        void* p = ws + off;
        off += (b + 255) & ~(size_t)255;
        return p;
    };
    int*      bucket_cur  = (int*)alloc((NB + 16) * 4);   // [0..NB) bucket cursors, [NB+4..NB+12) slice queues
    int*      deg         = (int*)alloc((size_t)NN * 4);
    float*    inv_deg     = (float*)alloc((size_t)NN * 4);
    int*      row_start   = (int*)alloc((size_t)NN * 4);
    int*      csr         = (int*)alloc((size_t)NB * BCAP * 4);   // 6.4 MB, bucket-strided
    uint32_t* xb          = (uint32_t*)alloc((size_t)NN * 64 * 4);
    uint16_t* bias_buf    = (uint16_t*)alloc(384 * 2);
    uint16_t* agg         = (uint16_t*)alloc((size_t)NN * 128 * 2);
    uint16_t* t           = (uint16_t*)alloc((size_t)NN * 128 * 2);
    float*    u           = (float*)alloc((size_t)NN * 128 * 4);
    uint16_t* w1l_sw      = (uint16_t*)alloc(128 * 256 * 2);
    uint16_t* w1r_sw      = (uint16_t*)alloc(128 * 256 * 2);
    uint16_t* w2l_sw      = (uint16_t*)alloc(256 * 128 * 2);
    uint16_t* w2r_sw      = (uint16_t*)alloc(256 * 128 * 2);

    int* qctr = bucket_cur + NB + 4;   // 8 slice-queue counters, zeroed by the same memset

    // staging aliases t (6.4 MB <= 12.8 MB; fully consumed by csr_norm before t is written)
    uint32_t* staging = (uint32_t*)t;

    hipMemsetAsync(bucket_cur, 0, (NB + 16) * 4, stream);
    scatter1<<<NBLK, 256, 0, stream>>>(ei, bucket_cur, staging);
    csr_norm<<<NB + NORMX_BLKS + 66, 256, 0, stream>>>(staging, bucket_cur, x_raw,
                                                       W1l, b1, W1r, W2l, b2, W2r,
                                                       row_start, deg, inv_deg, csr,
                                                       xb, w1l_sw, w1r_sw, w2l_sw, w2r_sw, bias_buf);

    // layer 1 agg (control, unchanged), fused MLP (round-8 shape), XCD-affine final agg (experiment)
    agg_mean_v2<<<NN / 8, 256, 0, stream>>>(xb, row_start, deg, csr, inv_deg, (uint32_t*)agg);
    fused_mlp<<<782, 512, 0, stream>>>(agg, (const uint16_t*)xb,
                                       w1l_sw, w1r_sw, w2l_sw, w2r_sw, bias_buf, t, u);
    agg_final_q<<<2048, 256, 0, stream>>>((const uint32_t*)t, row_start, deg, csr, inv_deg,
                                          u, qctr, (float*)d_out);
}

// Round 13
// 236.927 us; speedup vs baseline: 2.1397x; 2.1397x over previous
//
#include <hip/hip_runtime.h>
#include <hip/hip_bf16.h>
#include <stdint.h>

#define NN 50000
#define NE 800000
#define NB 196            // dst buckets: dst>>8 (256 nodes each)
#define EPB 2048
#define NBLK ((NE + EPB - 1) / EPB)   // 391
#define BCAP 8192         // per-bucket staging capacity (max bucket ~4350)

typedef __attribute__((ext_vector_type(8))) __bf16 bf16x8;
typedef __attribute__((ext_vector_type(4))) float f32x4;
typedef __attribute__((ext_vector_type(4))) int i32x4;
typedef __attribute__((ext_vector_type(2))) uint32_t u32x2;

__device__ __forceinline__ float bflo(uint32_t u) { return __uint_as_float(u << 16); }
__device__ __forceinline__ float bfhi(uint32_t u) { return __uint_as_float(u & 0xffff0000u); }
__device__ __forceinline__ uint16_t f2bf(float f) {
    uint32_t u = __float_as_uint(f);
    u += 0x7fffu + ((u >> 16) & 1u);   // RNE
    return (uint16_t)(u >> 16);
}
__device__ __forceinline__ float bf2f(uint16_t h) { return __uint_as_float(((uint32_t)h) << 16); }

// bijective XCD-chunked block swizzle (m204 variant)
__device__ __forceinline__ int xcd_swz(int bid, int nwg) {
    int q = nwg >> 3, r = nwg & 7;
    int xcd = bid & 7, idx = bid >> 3;
    int base = (xcd < r) ? xcd * (q + 1) : r * (q + 1) + (xcd - r) * q;
    return base + idx;
}

// per-block edge-layout detection (int64 vs int32)
__device__ __forceinline__ int detect_i64(const int* ei, int* sh_cnt) {
    int t = threadIdx.x;
    if (t == 0) *sh_cnt = 0;
    __syncthreads();
    if (t < 64) atomicAdd(sh_cnt, (ei[2 * t + 1] != 0) ? 1 : 0);
    __syncthreads();
    return (*sh_cnt < 4) ? 1 : 0;
}

// per-block x-dtype detection (fp32 vs bf16)
__device__ __forceinline__ int detect_fp32(const uint32_t* xu, int* sh_cnt) {
    int t = threadIdx.x;
    if (t == 0) *sh_cnt = 0;
    __syncthreads();
    uint32_t u = xu[t & 255];
    uint32_t lo = u & 0xffffu;
    uint32_t e = (lo >> 7) & 0xffu;
    int ok = (lo == 0u) || (e >= 96u && e <= 150u);
    if (t < 256) atomicAdd(sh_cnt, ok);
    __syncthreads();
    return (*sh_cnt < 192) ? 1 : 0;
}

// ---------------- prep kernel 1: count + reserve + scatter (single kernel) ----------------
__global__ __launch_bounds__(256) void scatter1(const int* __restrict__ ei,
                                                int* __restrict__ bucket_cur,
                                                uint32_t* __restrict__ staging) {
    __shared__ int hist[NB];
    __shared__ int curs[NB];
    __shared__ int shc;
    int fl = detect_i64(ei, &shc);
    int t = threadIdx.x;
    for (int i = t; i < NB; i += 256) hist[i] = 0;
    __syncthreads();
    int base = blockIdx.x * EPB;
    for (int i = 0; i < EPB; i += 256) {   // pass 1: count
        int e = base + i + t;
        if (e < NE) {
            int d = fl ? ei[2 * NE + 2 * e] : ei[NE + e];
            atomicAdd(&hist[d >> 8], 1);
        }
    }
    __syncthreads();
    for (int i = t; i < NB; i += 256)      // reserve runs
        curs[i] = (hist[i] > 0) ? atomicAdd(&bucket_cur[i], hist[i]) : 0;
    __syncthreads();
    for (int i = 0; i < EPB; i += 256) {   // pass 2: scatter (ei re-read from L2)
        int e = base + i + t;
        if (e < NE) {
            int s, d;
            if (fl) { s = ei[2 * e]; d = ei[2 * NE + 2 * e]; }
            else    { s = ei[e];     d = ei[NE + e]; }
            int b = d >> 8;
            int p = atomicAdd(&curs[b], 1);
            staging[b * BCAP + p] = ((uint32_t)(d & 0xff) << 16) | (uint32_t)s;
        }
    }
}

// ---------------- prep kernel 2 (role-split): CSR build + x-norm + weight swizzle ----------------
#define NORMX_BLKS 6250   // NN*32/256
__global__ __launch_bounds__(256) void csr_norm(const uint32_t* __restrict__ staging,
                                                const int* __restrict__ bucket_cur,
                                                const void* __restrict__ x,
                                                const void* __restrict__ w1l, const void* __restrict__ b1,
                                                const void* __restrict__ w1r, const void* __restrict__ w2l,
                                                const void* __restrict__ b2, const void* __restrict__ w2r,
                                                int* __restrict__ row_start, int* __restrict__ deg,
                                                float* __restrict__ inv_deg, int* __restrict__ csr,
                                                uint32_t* __restrict__ xb,
                                                uint16_t* __restrict__ w1l_sw, uint16_t* __restrict__ w1r_sw,
                                                uint16_t* __restrict__ w2l_sw, uint16_t* __restrict__ w2r_sw,
                                                uint16_t* __restrict__ bias_buf) {
    int blk = blockIdx.x;
    int t = threadIdx.x;
    if (blk < NB) {
        __shared__ int degs[256];
        __shared__ int sm[256];
        __shared__ int curs[256];
        int beg = blk * BCAP, cnt = bucket_cur[blk];
        degs[t] = 0;
        __syncthreads();
        for (int i = t; i < cnt; i += 256) atomicAdd(&degs[(staging[beg + i] >> 16) & 0xff], 1);
        __syncthreads();
        int d = degs[t];
        sm[t] = d;
        __syncthreads();
        for (int o = 1; o < 256; o <<= 1) {
            int x2 = (t >= o) ? sm[t - o] : 0;
            __syncthreads();
            sm[t] += x2;
            __syncthreads();
        }
        int excl = sm[t] - d;
        curs[t] = excl;
        int node = blk * 256 + t;
        if (node < NN) {
            row_start[node] = beg + excl;
            deg[node] = d;
            inv_deg[node] = 1.0f / (float)(d > 0 ? d : 1);
        }
        __syncthreads();
        for (int i = t; i < cnt; i += 256) {
            uint32_t u = staging[beg + i];
            int dl = (u >> 16) & 0xff;
            int p = atomicAdd(&curs[dl], 1);
            csr[beg + p] = (int)(u & 0xffffu);
        }
        return;
    }
    __shared__ int shc;
    int fp32 = detect_fp32((const uint32_t*)x, &shc);
    int nb = blk - NB;
    if (nb < NORMX_BLKS) {
        int i = nb * 256 + t;  // < NN*32
        if (fp32) {
            f32x4 v = ((const f32x4*)x)[i];
            uint2 o;
            o.x = (uint32_t)f2bf(v[0]) | ((uint32_t)f2bf(v[1]) << 16);
            o.y = (uint32_t)f2bf(v[2]) | ((uint32_t)f2bf(v[3]) << 16);
            ((uint2*)xb)[i] = o;
        } else {
            ((uint2*)xb)[i] = ((const uint2*)x)[i];
        }
        return;
    }
    int tid = (nb - NORMX_BLKS) * 256 + t;
    if (tid < 16384) {
        int frag = tid >> 6, lane = tid & 63;
        const void* srcw; uint16_t* dst; int N; int fl;
        if (frag < 64)       { srcw = w1l; dst = w1l_sw; N = 256; fl = frag; }
        else if (frag < 128) { srcw = w1r; dst = w1r_sw; N = 256; fl = frag - 64; }
        else if (frag < 192) { srcw = w2l; dst = w2l_sw; N = 128; fl = frag - 128; }
        else                 { srcw = w2r; dst = w2r_sw; N = 128; fl = frag - 192; }
        int NTm = N >> 4;
        int kt = fl / NTm, nt = fl - kt * NTm;
        int k0 = kt * 32 + (lane >> 4) * 8, n = nt * 16 + (lane & 15);
        uint16_t* d = dst + (size_t)fl * 512 + lane * 8;
#pragma unroll
        for (int j = 0; j < 8; j++) {
            int si = (k0 + j) * N + n;
            d[j] = fp32 ? f2bf(((const float*)srcw)[si]) : ((const uint16_t*)srcw)[si];
        }
    } else if (tid < 16384 + 384) {
        int j = tid - 16384;
        const void* s = (j < 256) ? b1 : b2;
        int jj = (j < 256) ? j : j - 256;
        bias_buf[j] = fp32 ? f2bf(((const float*)s)[jj]) : ((const uint16_t*)s)[jj];
    }
}

// ---------------- mean aggregation v2: 2 nodes/wave, dwordx2 gathers; NT output ----------------
__global__ __launch_bounds__(256) void agg_mean_v2(const uint32_t* __restrict__ xu,
                                                   const int* __restrict__ row_start,
                                                   const int* __restrict__ deg,
                                                   const int* __restrict__ csr,
                                                   const float* __restrict__ inv_deg,
                                                   uint32_t* __restrict__ outu) {
    int wave = threadIdx.x >> 6, lane = threadIdx.x & 63;
    int half = lane >> 5, l = lane & 31;
    int node = blockIdx.x * 8 + wave * 2 + half;
    int beg = row_start[node], end = beg + deg[node];
    float lx[8], hx[8], ly[8], hy[8];
#pragma unroll
    for (int k = 0; k < 8; k++) { lx[k] = 0.f; hx[k] = 0.f; ly[k] = 0.f; hy[k] = 0.f; }
    int j = beg;
    for (; j + 8 <= end; j += 8) {
        int idx[8];
#pragma unroll
        for (int k = 0; k < 8; k++) idx[k] = csr[j + k];
#pragma unroll
        for (int k = 0; k < 8; k++) {
            uint2 v = *(const uint2*)(xu + (size_t)idx[k] * 64 + l * 2);
            lx[k] += bflo(v.x); hx[k] += bfhi(v.x);
            ly[k] += bflo(v.y); hy[k] += bfhi(v.y);
        }
    }
    for (; j < end; j++) {
        uint2 v = *(const uint2*)(xu + (size_t)csr[j] * 64 + l * 2);
        lx[0] += bflo(v.x); hx[0] += bfhi(v.x);
        ly[0] += bflo(v.y); hy[0] += bfhi(v.y);
    }
    float sc = inv_deg[node];
    float r0 = (((lx[0] + lx[1]) + (lx[2] + lx[3])) + ((lx[4] + lx[5]) + (lx[6] + lx[7]))) * sc;
    float r1 = (((hx[0] + hx[1]) + (hx[2] + hx[3])) + ((hx[4] + hx[5]) + (hx[6] + hx[7]))) * sc;
    float r2 = (((ly[0] + ly[1]) + (ly[2] + ly[3])) + ((ly[4] + ly[5]) + (ly[6] + ly[7]))) * sc;
    float r3 = (((hy[0] + hy[1]) + (hy[2] + hy[3])) + ((hy[4] + hy[5]) + (hy[6] + hy[7]))) * sc;
    u32x2 o;
    o[0] = (uint32_t)f2bf(r0) | ((uint32_t)f2bf(r1) << 16);
    o[1] = (uint32_t)f2bf(r2) | ((uint32_t)f2bf(r3) << 16);
    __builtin_nontemporal_store(o, (u32x2*)(outu + (size_t)node * 64 + l * 2));
}

// final v2: out = mean_gather(t) + u; NT u-load and NT out-store keep t hot in L2 ----------------
__global__ __launch_bounds__(256) void agg_final_v2(const uint32_t* __restrict__ tu,
                                                    const int* __restrict__ row_start,
                                                    const int* __restrict__ deg,
                                                    const int* __restrict__ csr,
                                                    const float* __restrict__ inv_deg,
                                                    const f32x4* __restrict__ u,
                                                    f32x4* __restrict__ out) {
    int wave = threadIdx.x >> 6, lane = threadIdx.x & 63;
    int half = lane >> 5, l = lane & 31;
    int node = blockIdx.x * 8 + wave * 2 + half;
    int beg = row_start[node], end = beg + deg[node];
    float lx[8], hx[8], ly[8], hy[8];
#pragma unroll
    for (int k = 0; k < 8; k++) { lx[k] = 0.f; hx[k] = 0.f; ly[k] = 0.f; hy[k] = 0.f; }
    int j = beg;
    for (; j + 8 <= end; j += 8) {
        int idx[8];
#pragma unroll
        for (int k = 0; k < 8; k++) idx[k] = csr[j + k];
#pragma unroll
        for (int k = 0; k < 8; k++) {
            uint2 v = *(const uint2*)(tu + (size_t)idx[k] * 64 + l * 2);
            lx[k] += bflo(v.x); hx[k] += bfhi(v.x);
            ly[k] += bflo(v.y); hy[k] += bfhi(v.y);
        }
    }
    for (; j < end; j++) {
        uint2 v = *(const uint2*)(tu + (size_t)csr[j] * 64 + l * 2);
        lx[0] += bflo(v.x); hx[0] += bfhi(v.x);
        ly[0] += bflo(v.y); hy[0] += bfhi(v.y);
    }
    float sc = inv_deg[node];
    f32x4 uv = __builtin_nontemporal_load(&u[(size_t)node * 32 + l]);
    f32x4 r;
    r[0] = (((lx[0] + lx[1]) + (lx[2] + lx[3])) + ((lx[4] + lx[5]) + (lx[6] + lx[7]))) * sc + uv[0];
    r[1] = (((hx[0] + hx[1]) + (hx[2] + hx[3])) + ((hx[4] + hx[5]) + (hx[6] + hx[7]))) * sc + uv[1];
    r[2] = (((ly[0] + ly[1]) + (ly[2] + ly[3])) + ((ly[4] + ly[5]) + (ly[6] + ly[7]))) * sc + uv[2];
    r[3] = (((hy[0] + hy[1]) + (hy[2] + hy[3])) + ((hy[4] + hy[5]) + (hy[6] + hy[7]))) * sc + uv[3];
    __builtin_nontemporal_store(r, &out[(size_t)node * 32 + l]);
}

// ---------------- fused MLP (round-8 optimum, 64 rows x 8 waves): h(LDS) -> t, u ----------------
#define HW 264
__global__ __launch_bounds__(512) void fused_mlp(const uint16_t* __restrict__ AGG,
                                                 const uint16_t* __restrict__ XB,
                                                 const uint16_t* __restrict__ W1Lsw,
                                                 const uint16_t* __restrict__ W1Rsw,
                                                 const uint16_t* __restrict__ W2Lsw,
                                                 const uint16_t* __restrict__ W2Rsw,
                                                 const uint16_t* __restrict__ bias,   // [0..255]=b1, [256..383]=b2
                                                 uint16_t* __restrict__ T,
                                                 float* __restrict__ U) {
    __shared__ __align__(16) uint16_t hbuf[64 * HW];   // 33792 B, reused 3 ways
    int wg = xcd_swz(blockIdx.x, 782);
    int node0 = wg * 64;
    int tid = threadIdx.x;
    int wave = tid >> 6, lane = tid & 63;
    int wr = wave >> 2, wc = wave & 3;   // 2 row-halves x 4 col-quarters
    int m = lane & 15, q = lane >> 4;

    int ar[2];
#pragma unroll
    for (int rf = 0; rf < 2; rf++) {
        int r = node0 + wr * 32 + rf * 16 + m;
        ar[rf] = (r < NN) ? r : (NN - 1);
    }

    // ---- phase 1: h[64][256] = relu(agg@W1l + x@W1r + b1); wave tile 32x64 ----
    {
        f32x4 acc[2][4];
#pragma unroll
        for (int rf = 0; rf < 2; rf++)
#pragma unroll
            for (int nt = 0; nt < 4; nt++)
#pragma unroll
                for (int i = 0; i < 4; i++) acc[rf][nt][i] = 0.f;

#pragma unroll
        for (int kt = 0; kt < 4; kt++) {
            bf16x8 a10 = *(const bf16x8*)(AGG + (size_t)ar[0] * 128 + kt * 32 + q * 8);
            bf16x8 a11 = *(const bf16x8*)(AGG + (size_t)ar[1] * 128 + kt * 32 + q * 8);
            bf16x8 a20 = *(const bf16x8*)(XB + (size_t)ar[0] * 128 + kt * 32 + q * 8);
            bf16x8 a21 = *(const bf16x8*)(XB + (size_t)ar[1] * 128 + kt * 32 + q * 8);
#pragma unroll
            for (int nt = 0; nt < 4; nt++) {
                int gnt = wc * 4 + nt;   // NTF=16
                bf16x8 B1 = *(const bf16x8*)(W1Lsw + ((size_t)(kt * 16 + gnt)) * 512 + lane * 8);
                bf16x8 B2 = *(const bf16x8*)(W1Rsw + ((size_t)(kt * 16 + gnt)) * 512 + lane * 8);
                acc[0][nt] = __builtin_amdgcn_mfma_f32_16x16x32_bf16(a10, B1, acc[0][nt], 0, 0, 0);
                acc[1][nt] = __builtin_amdgcn_mfma_f32_16x16x32_bf16(a11, B1, acc[1][nt], 0, 0, 0);
                acc[0][nt] = __builtin_amdgcn_mfma_f32_16x16x32_bf16(a20, B2, acc[0][nt], 0, 0, 0);
                acc[1][nt] = __builtin_amdgcn_mfma_f32_16x16x32_bf16(a21, B2, acc[1][nt], 0, 0, 0);
            }
        }
        // epilogue 1: bias + relu -> hbuf
#pragma unroll
        for (int rf = 0; rf < 2; rf++)
#pragma unroll
            for (int nt = 0; nt < 4; nt++) {
                int cl = wc * 64 + nt * 16 + m;
                float bv = bf2f(bias[cl]);
#pragma unroll
                for (int i = 0; i < 4; i++) {
                    float v = fmaxf(acc[rf][nt][i] + bv, 0.f);
                    hbuf[(wr * 32 + rf * 16 + q * 4 + i) * HW + cl] = f2bf(v);
                }
            }
    }
    __syncthreads();

    // ---- phase 2: t = h@W2l, u = h@W2r + b2; wave tile 32x32 each, K=256 from LDS ----
    f32x4 acc1[2][2], acc2[2][2];
#pragma unroll
    for (int rf = 0; rf < 2; rf++)
#pragma unroll
        for (int nt = 0; nt < 2; nt++)
#pragma unroll
            for (int i = 0; i < 4; i++) { acc1[rf][nt][i] = 0.f; acc2[rf][nt][i] = 0.f; }

#pragma unroll
    for (int kt = 0; kt < 8; kt++) {
        bf16x8 a0 = *(const bf16x8*)&hbuf[(wr * 32 + m) * HW + kt * 32 + q * 8];
        bf16x8 a1 = *(const bf16x8*)&hbuf[(wr * 32 + 16 + m) * HW + kt * 32 + q * 8];
#pragma unroll
        for (int nt = 0; nt < 2; nt++) {
            int gnt = wc * 2 + nt;   // NTF=8
            bf16x8 BL = *(const bf16x8*)(W2Lsw + ((size_t)(kt * 8 + gnt)) * 512 + lane * 8);
            bf16x8 BR = *(const bf16x8*)(W2Rsw + ((size_t)(kt * 8 + gnt)) * 512 + lane * 8);
            acc1[0][nt] = __builtin_amdgcn_mfma_f32_16x16x32_bf16(a0, BL, acc1[0][nt], 0, 0, 0);
            acc1[1][nt] = __builtin_amdgcn_mfma_f32_16x16x32_bf16(a1, BL, acc1[1][nt], 0, 0, 0);
            acc2[0][nt] = __builtin_amdgcn_mfma_f32_16x16x32_bf16(a0, BR, acc2[0][nt], 0, 0, 0);
            acc2[1][nt] = __builtin_amdgcn_mfma_f32_16x16x32_bf16(a1, BR, acc2[1][nt], 0, 0, 0);
        }
    }
    __syncthreads();   // all waves done reading hbuf

    // ---- epilogue t: stage bf16 [64][136] in hbuf, coalesced store ----
    {
        uint16_t* st = hbuf;   // [64][136] = 17408 B
#pragma unroll
        for (int rf = 0; rf < 2; rf++)
#pragma unroll
            for (int nt = 0; nt < 2; nt++) {
                int cl = wc * 32 + nt * 16 + m;
#pragma unroll
                for (int i = 0; i < 4; i++)
                    st[(wr * 32 + rf * 16 + q * 4 + i) * 136 + cl] = f2bf(acc1[rf][nt][i]);
            }
        __syncthreads();
#pragma unroll
        for (int rr = 0; rr < 2; rr++) {
            int row = rr * 32 + (tid >> 4);
            int grow = node0 + row;
            if (grow < NN)
                *(i32x4*)(T + (size_t)grow * 128 + (tid & 15) * 8) =
                    *(const i32x4*)&st[row * 136 + (tid & 15) * 8];
        }
        __syncthreads();
    }

    // ---- epilogue u: stage fp32 [64][132] in hbuf, coalesced store ----
    {
        float* su = (float*)hbuf;   // [64][132] = 33792 B (exactly hbuf)
#pragma unroll
        for (int rf = 0; rf < 2; rf++)
#pragma unroll
            for (int nt = 0; nt < 2; nt++) {
                int cl = wc * 32 + nt * 16 + m;
                float bv = bf2f(bias[256 + cl]);
#pragma unroll
                for (int i = 0; i < 4; i++)
                    su[(wr * 32 + rf * 16 + q * 4 + i) * 132 + cl] = acc2[rf][nt][i] + bv;
            }
        __syncthreads();
#pragma unroll
        for (int rr = 0; rr < 4; rr++) {
            int row = rr * 16 + (tid >> 5);
            int grow = node0 + row;
            if (grow < NN)
                *(f32x4*)(U + (size_t)grow * 128 + (tid & 31) * 4) =
                    *(const f32x4*)&su[row * 132 + (tid & 31) * 4];
        }
    }
}

extern "C" void kernel_launch(void* const* d_in, const int* in_sizes, int n_in,
                              void* d_out, int out_size, void* d_ws, size_t ws_size,
                              hipStream_t stream) {
    const void* x_raw  = d_in[0];
    const int*  ei     = (const int*)d_in[1];
    const void* W1l    = d_in[2];
    const void* b1     = d_in[3];
    const void* W1r    = d_in[4];
    const void* W2l    = d_in[5];
    const void* b2     = d_in[6];
    const void* W2r    = d_in[7];

    uint8_t* ws = (uint8_t*)d_ws;
    size_t off = 0;
    auto alloc = [&](size_t b) -> void* {
        void* p = ws + off;
        off += (b + 255) & ~(size_t)255;
        return p;
    };
    int*      bucket_cur  = (int*)alloc((NB + 4) * 4);
    int*      deg         = (int*)alloc((size_t)NN * 4);
    float*    inv_deg     = (float*)alloc((size_t)NN * 4);
    int*      row_start   = (int*)alloc((size_t)NN * 4);
    int*      csr         = (int*)alloc((size_t)NB * BCAP * 4);   // 6.4 MB, bucket-strided
    uint32_t* xb          = (uint32_t*)alloc((size_t)NN * 64 * 4);
    uint16_t* bias_buf    = (uint16_t*)alloc(384 * 2);
    uint16_t* agg         = (uint16_t*)alloc((size_t)NN * 128 * 2);
    uint16_t* t           = (uint16_t*)alloc((size_t)NN * 128 * 2);
    float*    u           = (float*)alloc((size_t)NN * 128 * 4);
    uint16_t* w1l_sw      = (uint16_t*)alloc(128 * 256 * 2);
    uint16_t* w1r_sw      = (uint16_t*)alloc(128 * 256 * 2);
    uint16_t* w2l_sw      = (uint16_t*)alloc(256 * 128 * 2);
    uint16_t* w2r_sw      = (uint16_t*)alloc(256 * 128 * 2);

    // staging aliases t (6.4 MB <= 12.8 MB; fully consumed by csr_norm before t is written)
    uint32_t* staging = (uint32_t*)t;

    (void)hipMemsetAsync(bucket_cur, 0, (NB + 4) * 4, stream);
    scatter1<<<NBLK, 256, 0, stream>>>(ei, bucket_cur, staging);
    csr_norm<<<NB + NORMX_BLKS + 66, 256, 0, stream>>>(staging, bucket_cur, x_raw,
                                                       W1l, b1, W1r, W2l, b2, W2r,
                                                       row_start, deg, inv_deg, csr,
                                                       xb, w1l_sw, w1r_sw, w2l_sw, w2r_sw, bias_buf);

    // layer 1 agg, then fused MLP (h stays in LDS), then final agg
    agg_mean_v2<<<NN / 8, 256, 0, stream>>>(xb, row_start, deg, csr, inv_deg, (uint32_t*)agg);
    fused_mlp<<<782, 512, 0, stream>>>(agg, (const uint16_t*)xb,
                                       w1l_sw, w1r_sw, w2l_sw, w2r_sw, bias_buf, t, u);
    agg_final_v2<<<NN / 8, 256, 0, stream>>>((const uint32_t*)t, row_start, deg, csr, inv_deg,
                                             (const f32x4*)u, (f32x4*)d_out);
}